// Round 15
// baseline (194.523 us; speedup 1.0000x reference)
//
#include <hip/hip_runtime.h>
#include <math.h>

#define NDIR 5
#define E_ 16
#define W_ 3
#define D_ 128
#define P_ 256
#define B_ 4
#define ROWS 64
#define NPQ 4
#define STEPS 24   // W_ * 8 k8-steps

typedef __attribute__((ext_vector_type(8))) short short8;
typedef __attribute__((ext_vector_type(4))) float f32x4;
typedef __attribute__((ext_vector_type(8))) float f32x8;

struct RoutesArg { int r[E_][W_]; };

// Replicates Python _cantor_coord + stable argsort route construction on host.
static RoutesArg make_routes() {
    float coords[E_];
    for (int i = 0; i < E_; ++i) {
        double x = (double)i / (double)(E_ - 1);
        if (x < 1e-6) x = 1e-6;
        if (x > 1.0 - 1e-6) x = 1.0 - 1e-6;
        double val = 0.0, factor = 0.5;
        for (int d = 0; d < 8; ++d) {
            x *= 3.0;
            int digit = (int)x;
            x -= (double)digit;
            if (digit == 2) val += factor;
            factor *= 0.5;
        }
        coords[i] = (float)val;
    }
    RoutesArg R;
    for (int i = 0; i < E_; ++i) {
        float d[E_]; int idx[E_];
        for (int j = 0; j < E_; ++j) { d[j] = fabsf(coords[j] - coords[i]); idx[j] = j; }
        for (int a = 1; a < E_; ++a) {
            int key = idx[a]; float kd = d[key];
            int c = a - 1;
            while (c >= 0 && d[idx[c]] > kd) { idx[c + 1] = idx[c]; --c; }
            idx[c + 1] = key;
        }
        int top[W_] = { idx[0], idx[1], idx[2] };
        if (top[0] > top[1]) { int t = top[0]; top[0] = top[1]; top[1] = t; }
        if (top[1] > top[2]) { int t = top[1]; top[1] = top[2]; top[2] = t; }
        if (top[0] > top[1]) { int t = top[0]; top[0] = top[1]; top[1] = t; }
        for (int w = 0; w < W_; ++w) R.r[i][w] = top[w];
    }
    return R;
}

// exact RNE float->bf16 (finite inputs only)
static __device__ __forceinline__ unsigned short f2bf(float f) {
    union { float f; unsigned int u; } v; v.f = f;
    unsigned int r = (v.u + 0x7FFFu + ((v.u >> 16) & 1u)) >> 16;
    return (unsigned short)r;
}

// HW packed f32->bf16 (RNE), proven correct in Rounds 6/7/12/13.
static __device__ __forceinline__ unsigned int cvt_pk_bf16(float lo, float hi) {
    unsigned int r;
    asm("v_cvt_pk_bf16_f32 %0, %1, %2" : "=v"(r) : "v"(lo), "v"(hi));
    return r;
}

// By-VALUE vector in, literal indices only -> stays in registers (rule #20).
static __device__ __forceinline__ short8 pack8(f32x8 a) {
    union { unsigned int u[4]; short8 s; } cv;
    cv.u[0] = cvt_pk_bf16(a[0], a[1]);
    cv.u[1] = cvt_pk_bf16(a[2], a[3]);
    cv.u[2] = cvt_pk_bf16(a[4], a[5]);
    cv.u[3] = cvt_pk_bf16(a[6], a[7]);
    return cv.s;
}

static __device__ __forceinline__ short8 u4_to_s8(uint4 u) {
    union { uint4 u; short8 s; } cv; cv.u = u; return cv.s;
}

// ---- prep: V fp32 [slab][k=256][f=128] -> Vt bf16 [slab][f=128][k=256] ----
__global__ __launch_bounds__(256) void vt_prep_kernel(
    const float* __restrict__ V, unsigned short* __restrict__ Vt)
{
    const int sub  = blockIdx.x & 3;          // k-quarter
    const int slab = blockIdx.x >> 2;         // 0..319
    const int tid  = threadIdx.x;
    const float4* __restrict__ src =
        reinterpret_cast<const float4*>(V + (size_t)slab * (P_ * D_));
    unsigned short* __restrict__ dst = Vt + (size_t)slab * (P_ * D_);
    #pragma unroll
    for (int it = 0; it < 8; ++it) {
        const int idx4 = sub * 2048 + it * 256 + tid;
        const int k  = idx4 >> 5;
        const int f4 = (idx4 & 31) * 4;
        const float4 v = src[idx4];
        dst[(size_t)(f4 + 0) * P_ + k] = f2bf(v.x);
        dst[(size_t)(f4 + 1) * P_ + k] = f2bf(v.y);
        dst[(size_t)(f4 + 2) * P_ + k] = f2bf(v.z);
        dst[(size_t)(f4 + 3) * P_ + k] = f2bf(v.w);
    }
}

// Block = (x, e, b, pq-tile of 64 rows); 1280 blocks, 4 waves.
// wave = 16-row quarter x all 128 cols -> zero exp duplication.
// B-fragments: single uint4 loads from pre-transposed bf16 Vt (no B-pack).
// sched_barrier(0) after each prefetch group pins the software pipeline
// (R12/R14 showed the compiler sinks the loads otherwise -> serial latency).
template <bool ATOMIC>
__global__ __launch_bounds__(256, 4) void cantor_partial2_kernel(
    const float* __restrict__ Q, const float* __restrict__ K,
    const unsigned short* __restrict__ Vt, const float* __restrict__ betas,
    const float* __restrict__ temperature, const float* __restrict__ fusion,
    float* __restrict__ target, RoutesArg routes)
{
    __shared__ float s_lds[W_ * P_];   // 3 KB

    // XCD-bijective swizzle: 1280 blocks = 8 XCDs x 160
    const int orig = blockIdx.x;
    const int wg   = (orig & 7) * 160 + (orig >> 3);

    const int pq = wg & 3;
    const int b  = (wg >> 2) & 3;
    const int e  = (wg >> 4) & 15;
    const int x  = wg >> 8;

    const int tid  = threadIdx.x;
    const int lane = tid & 63;
    const int wv   = tid >> 6;
    const int l15  = lane & 15;
    const int lg   = lane >> 4;

    const int rowbase = wv * 16;   // wave's 16-row quarter

    const float temp = fabsf(temperature[0]) + 1e-6f;

    // fusion softmax -> weight for this x
    float fwx;
    {
        float fv[NDIR], fmx = -1e30f, fsum = 0.f;
        #pragma unroll
        for (int i = 0; i < NDIR; ++i) { fv[i] = fusion[i]; fmx = fmaxf(fmx, fv[i]); }
        #pragma unroll
        for (int i = 0; i < NDIR; ++i) { fv[i] = __expf(fv[i] - fmx); fsum += fv[i]; }
        fwx = fv[x] / fsum;
    }

    int rt[W_]; float bf3[W_];
    #pragma unroll
    for (int w = 0; w < W_; ++w) {
        rt[w] = routes.r[e][w];
        float bv_ = betas[e * E_ + rt[w]];
        bf3[w] = (rt[w] == e) ? 1.0f : 1.0f / (1.0f + __expf(-bv_));
    }

    // stage s = K * beta (768 floats)
    #pragma unroll
    for (int w = 0; w < W_; ++w)
        s_lds[w * P_ + tid] =
            K[(((size_t)(x * E_ + rt[w])) * B_ + b) * P_ + tid] * bf3[w];

    // this lane's q row (one 16-row fragment per wave)
    const float q1 =
        Q[(((size_t)(x * E_ + e)) * B_ + b) * P_ + pq * ROWS + rowbase + l15] / temp;

    // per-route Vt base pointers in uint4 units, pre-offset by l15*32 + lg
    const uint4* vt0 = reinterpret_cast<const uint4*>(Vt)
        + ((size_t)(x * E_ + rt[0]) * B_ + b) * (P_ * D_ / 8) + l15 * 32 + lg;
    const uint4* vt1 = reinterpret_cast<const uint4*>(Vt)
        + ((size_t)(x * E_ + rt[1]) * B_ + b) * (P_ * D_ / 8) + l15 * 32 + lg;
    const uint4* vt2 = reinterpret_cast<const uint4*>(Vt)
        + ((size_t)(x * E_ + rt[2]) * B_ + b) * (P_ * D_ / 8) + l15 * 32 + lg;
    const float* sp0 = s_lds + 0 * P_ + 8 * lg;
    const float* sp1 = s_lds + 1 * P_ + 8 * lg;
    const float* sp2 = s_lds + 2 * P_ + 8 * lg;

    __syncthreads();   // s_lds ready — the only barrier

    f32x4 acc[8];
    #pragma unroll
    for (int c = 0; c < 8; ++c) acc[c] = (f32x4){0.f, 0.f, 0.f, 0.f};
    float den = 0.f;

    // uint4 index for step g, col-group c: base(route) + (g&7)*4 + c*512
    #define VTP(g) (((g) < 8 ? vt0 : ((g) < 16 ? vt1 : vt2)) + (((g) & 7) * 4))
    #define SPTR(g) ((((g) < 8) ? sp0 : (((g) < 16) ? sp1 : sp2)) + (((g) & 7) * 32))

    #define LOADB(B0,B1,B2,B3,B4,B5,B6,B7, g) do {            \
        const uint4* p_ = VTP(g);                             \
        B0 = p_[0 * 512]; B1 = p_[1 * 512];                   \
        B2 = p_[2 * 512]; B3 = p_[3 * 512];                   \
        B4 = p_[4 * 512]; B5 = p_[5 * 512];                   \
        B6 = p_[6 * 512]; B7 = p_[7 * 512];                   \
    } while (0)

    #define AWORK(af_, g) do {                                           \
        const float* sp_ = SPTR(g);                                      \
        f32x8 sv_;                                                       \
        {                                                                \
            const float4 s0_ = *reinterpret_cast<const float4*>(sp_);    \
            const float4 s1_ = *reinterpret_cast<const float4*>(sp_ + 4);\
            sv_[0]=s0_.x; sv_[1]=s0_.y; sv_[2]=s0_.z; sv_[3]=s0_.w;      \
            sv_[4]=s1_.x; sv_[5]=s1_.y; sv_[6]=s1_.z; sv_[7]=s1_.w;      \
        }                                                                \
        f32x8 ev_;                                                       \
        _Pragma("unroll")                                                \
        for (int i_ = 0; i_ < 8; ++i_) ev_[i_] = __expf(q1 * sv_[i_]);   \
        den += ((ev_[0]+ev_[1]) + (ev_[2]+ev_[3])) +                     \
               ((ev_[4]+ev_[5]) + (ev_[6]+ev_[7]));                      \
        af_ = pack8(ev_);                                                \
    } while (0)

    #define MFMA8(B0,B1,B2,B3,B4,B5,B6,B7, af_) do {                                      \
        acc[0] = __builtin_amdgcn_mfma_f32_16x16x32_bf16(af_, u4_to_s8(B0), acc[0],0,0,0);\
        acc[1] = __builtin_amdgcn_mfma_f32_16x16x32_bf16(af_, u4_to_s8(B1), acc[1],0,0,0);\
        acc[2] = __builtin_amdgcn_mfma_f32_16x16x32_bf16(af_, u4_to_s8(B2), acc[2],0,0,0);\
        acc[3] = __builtin_amdgcn_mfma_f32_16x16x32_bf16(af_, u4_to_s8(B3), acc[3],0,0,0);\
        acc[4] = __builtin_amdgcn_mfma_f32_16x16x32_bf16(af_, u4_to_s8(B4), acc[4],0,0,0);\
        acc[5] = __builtin_amdgcn_mfma_f32_16x16x32_bf16(af_, u4_to_s8(B5), acc[5],0,0,0);\
        acc[6] = __builtin_amdgcn_mfma_f32_16x16x32_bf16(af_, u4_to_s8(B6), acc[6],0,0,0);\
        acc[7] = __builtin_amdgcn_mfma_f32_16x16x32_bf16(af_, u4_to_s8(B7), acc[7],0,0,0);\
    } while (0)

    uint4 a0,a1,a2,a3,a4,a5,a6,a7;   // buffer A
    uint4 b0,b1,b2,b3,b4,b5,b6,b7;   // buffer B
    short8 af;

    LOADB(a0,a1,a2,a3,a4,a5,a6,a7, 0);
    __builtin_amdgcn_sched_barrier(0);

    for (int gp = 0; gp < STEPS / 2; ++gp) {
        const int g0 = 2 * gp, g1 = 2 * gp + 1;
        // prefetch odd step, pinned above current compute
        LOADB(b0,b1,b2,b3,b4,b5,b6,b7, g1);
        __builtin_amdgcn_sched_barrier(0);
        AWORK(af, g0);
        MFMA8(a0,a1,a2,a3,a4,a5,a6,a7, af);      // consume buffer A
        __builtin_amdgcn_sched_barrier(0);
        // prefetch next even step (g=24 wraps to route2/k0 — in-bounds, unused)
        LOADB(a0,a1,a2,a3,a4,a5,a6,a7, g1 + 1);
        __builtin_amdgcn_sched_barrier(0);
        AWORK(af, g1);
        MFMA8(b0,b1,b2,b3,b4,b5,b6,b7, af);      // consume buffer B
        __builtin_amdgcn_sched_barrier(0);
    }
    #undef VTP
    #undef SPTR
    #undef LOADB
    #undef AWORK
    #undef MFMA8

    // ---- full-row denominator: sum across the 4 lane-groups ----
    den += __shfl_xor(den, 16);
    den += __shfl_xor(den, 32);

    // ---- scale + write (rows rowbase + 4*lg + r, cols c*16 + l15) ----
    const size_t obase = ((((size_t)b * E_ + e) * NPQ) + pq) * (ROWS * D_);
    float* __restrict__ tgt = ATOMIC
        ? target
        : target + (size_t)x * ((size_t)B_ * E_ * NPQ * ROWS * D_);

    #pragma unroll
    for (int r = 0; r < 4; ++r) {
        const float dr = __shfl(den, 4 * lg + r);   // den of row16 = 4*lg+r
        const float sc = fwx / dr;
        const int row = rowbase + 4 * lg + r;
        float* op = tgt + obase + (size_t)row * D_;
        #pragma unroll
        for (int c = 0; c < 8; ++c) {
            const float v = sc * acc[c][r];
            if (ATOMIC) atomicAdd(op + c * 16 + l15, v);
            else        op[c * 16 + l15] = v;
        }
    }
}

__global__ __launch_bounds__(256) void reduce5_kernel(
    const float* __restrict__ part, float* __restrict__ out)
{
    const size_t i = (size_t)blockIdx.x * 256 + threadIdx.x;   // float4 index
    const float4* __restrict__ p = reinterpret_cast<const float4*>(part);
    float4 a = p[i];
    #pragma unroll
    for (int x = 1; x < NDIR; ++x) {
        float4 t = p[(size_t)x * 524288 + i];
        a.x += t.x; a.y += t.y; a.z += t.z; a.w += t.w;
    }
    reinterpret_cast<float4*>(out)[i] = a;
}

extern "C" void kernel_launch(void* const* d_in, const int* in_sizes, int n_in,
                              void* d_out, int out_size, void* d_ws, size_t ws_size,
                              hipStream_t stream) {
    (void)in_sizes; (void)n_in;
    RoutesArg R = make_routes();
    const float* Q     = (const float*)d_in[0];
    const float* K     = (const float*)d_in[1];
    const float* V     = (const float*)d_in[2];
    const float* betas = (const float*)d_in[3];
    const float* tempr = (const float*)d_in[4];
    const float* fuse  = (const float*)d_in[5];
    float* out = (float*)d_out;

    const size_t vt_bytes   = (size_t)NDIR * E_ * B_ * P_ * D_ * 2;            // ~21 MB
    const size_t part_bytes = (size_t)NDIR * B_ * E_ * NPQ * ROWS * D_ * 4;    // ~42 MB

    dim3 grid(NDIR * E_ * B_ * NPQ);   // 1280
    dim3 block(256);

    if (ws_size >= vt_bytes + part_bytes) {
        unsigned short* Vt = (unsigned short*)d_ws;
        float* part = (float*)((char*)d_ws + vt_bytes);
        hipLaunchKernelGGL(vt_prep_kernel, dim3(1280), block, 0, stream, V, Vt);
        hipLaunchKernelGGL((cantor_partial2_kernel<false>), grid, block, 0, stream,
                           Q, K, Vt, betas, tempr, fuse, part, R);
        hipLaunchKernelGGL(reduce5_kernel, dim3(2048), block, 0, stream,
                           part, out);
    } else if (ws_size >= vt_bytes) {
        unsigned short* Vt = (unsigned short*)d_ws;
        (void)hipMemsetAsync(d_out, 0, (size_t)out_size * 4, stream);
        hipLaunchKernelGGL(vt_prep_kernel, dim3(1280), block, 0, stream, V, Vt);
        hipLaunchKernelGGL((cantor_partial2_kernel<true>), grid, block, 0, stream,
                           Q, K, Vt, betas, tempr, fuse, out, R);
    } else {
        (void)hipMemsetAsync(d_out, 0, (size_t)out_size * 4, stream);
        // last-resort: partial2 semantics require Vt; without ws we cannot run
        // the fast path — fall back to atomic accumulation over fp32 V via
        // the R13 structure is no longer carried; use Vt-in-out? Not possible.
        // In practice ws_size (>=63MB observed) always takes a path above.
        hipLaunchKernelGGL(vt_prep_kernel, dim3(1280), block, 0, stream, V,
                           (unsigned short*)d_ws);
        hipLaunchKernelGGL((cantor_partial2_kernel<true>), grid, block, 0, stream,
                           Q, K, (const unsigned short*)d_ws, betas, tempr, fuse, out, R);
    }
}

// Round 16
// 104.781 us; speedup vs baseline: 1.8565x; 1.8565x over previous
//
#include <hip/hip_runtime.h>
#include <math.h>

#define NDIR 5
#define E_ 16
#define W_ 3
#define D_ 128
#define P_ 256
#define B_ 4
#define ROWS 64
#define NPQ 4
#define NT 12        // k64-chunks: W_*P_/64

typedef __attribute__((ext_vector_type(8))) short short8;
typedef __attribute__((ext_vector_type(4))) float f32x4;
typedef __attribute__((ext_vector_type(8))) float f32x8;

struct RoutesArg { int r[E_][W_]; };

// Replicates Python _cantor_coord + stable argsort route construction on host.
static RoutesArg make_routes() {
    float coords[E_];
    for (int i = 0; i < E_; ++i) {
        double x = (double)i / (double)(E_ - 1);
        if (x < 1e-6) x = 1e-6;
        if (x > 1.0 - 1e-6) x = 1.0 - 1e-6;
        double val = 0.0, factor = 0.5;
        for (int d = 0; d < 8; ++d) {
            x *= 3.0;
            int digit = (int)x;
            x -= (double)digit;
            if (digit == 2) val += factor;
            factor *= 0.5;
        }
        coords[i] = (float)val;
    }
    RoutesArg R;
    for (int i = 0; i < E_; ++i) {
        float d[E_]; int idx[E_];
        for (int j = 0; j < E_; ++j) { d[j] = fabsf(coords[j] - coords[i]); idx[j] = j; }
        for (int a = 1; a < E_; ++a) {
            int key = idx[a]; float kd = d[key];
            int c = a - 1;
            while (c >= 0 && d[idx[c]] > kd) { idx[c + 1] = idx[c]; --c; }
            idx[c + 1] = key;
        }
        int top[W_] = { idx[0], idx[1], idx[2] };
        if (top[0] > top[1]) { int t = top[0]; top[0] = top[1]; top[1] = t; }
        if (top[1] > top[2]) { int t = top[1]; top[1] = top[2]; top[2] = t; }
        if (top[0] > top[1]) { int t = top[0]; top[0] = top[1]; top[1] = t; }
        for (int w = 0; w < W_; ++w) R.r[i][w] = top[w];
    }
    return R;
}

// exact RNE float->bf16 (finite inputs only)
static __device__ __forceinline__ unsigned short f2bf(float f) {
    union { float f; unsigned int u; } v; v.f = f;
    unsigned int r = (v.u + 0x7FFFu + ((v.u >> 16) & 1u)) >> 16;
    return (unsigned short)r;
}

// HW packed f32->bf16 (RNE), proven correct in Rounds 6/7/12/13.
static __device__ __forceinline__ unsigned int cvt_pk_bf16(float lo, float hi) {
    unsigned int r;
    asm("v_cvt_pk_bf16_f32 %0, %1, %2" : "=v"(r) : "v"(lo), "v"(hi));
    return r;
}

// By-VALUE vector in, literal indices only -> stays in registers (rule #20).
static __device__ __forceinline__ short8 pack8(f32x8 a) {
    union { unsigned int u[4]; short8 s; } cv;
    cv.u[0] = cvt_pk_bf16(a[0], a[1]);
    cv.u[1] = cvt_pk_bf16(a[2], a[3]);
    cv.u[2] = cvt_pk_bf16(a[4], a[5]);
    cv.u[3] = cvt_pk_bf16(a[6], a[7]);
    return cv.s;
}

// async global->LDS, 16B per lane (dest = wave-uniform base + lane*16)
static __device__ __forceinline__ void gld16(const void* g, void* l) {
    __builtin_amdgcn_global_load_lds(
        (const __attribute__((address_space(1))) unsigned int*)g,
        (__attribute__((address_space(3))) unsigned int*)l,
        16, 0, 0);
}

// ---- prep: V fp32 [slab][k=256][f=128] -> Vt bf16 [slab][f=128][k=256] ----
__global__ __launch_bounds__(256) void vt_prep_kernel(
    const float* __restrict__ V, unsigned short* __restrict__ Vt)
{
    const int sub  = blockIdx.x & 3;          // k-quarter
    const int slab = blockIdx.x >> 2;         // 0..319
    const int tid  = threadIdx.x;
    const float4* __restrict__ src =
        reinterpret_cast<const float4*>(V + (size_t)slab * (P_ * D_));
    unsigned short* __restrict__ dst = Vt + (size_t)slab * (P_ * D_);
    #pragma unroll
    for (int it = 0; it < 8; ++it) {
        const int idx4 = sub * 2048 + it * 256 + tid;
        const int k  = idx4 >> 5;
        const int f4 = (idx4 & 31) * 4;
        const float4 v = src[idx4];
        dst[(size_t)(f4 + 0) * P_ + k] = f2bf(v.x);
        dst[(size_t)(f4 + 1) * P_ + k] = f2bf(v.y);
        dst[(size_t)(f4 + 2) * P_ + k] = f2bf(v.z);
        dst[(size_t)(f4 + 3) * P_ + k] = f2bf(v.w);
    }
}

// Block = (x, e, b, pq-tile of 64 rows); 1280 blocks, 4 waves, 2x2 wave split
// (32-row half x 64-col half). Vt k64-tile [128f][64k] bf16 staged to LDS via
// global_load_lds (16KB, dbuf), XOR-swizzled source (slot ^= f&7) for 2-way
// reads. One barrier per chunk (m97/T3 structure) — loads for chunk t+1 fly
// during compute of t; barrier drain lands them.
template <bool ATOMIC>
__global__ __launch_bounds__(256) void cantor_partial3_kernel(
    const float* __restrict__ Q, const float* __restrict__ K,
    const unsigned short* __restrict__ Vt, const float* __restrict__ betas,
    const float* __restrict__ temperature, const float* __restrict__ fusion,
    float* __restrict__ target, RoutesArg routes)
{
    __shared__ float s_lds[W_ * P_];                         // 3 KB
    __shared__ __align__(16) unsigned char vbuf[2][16384];   // 32 KB

    // XCD-bijective swizzle: 1280 blocks = 8 XCDs x 160
    const int orig = blockIdx.x;
    const int wg   = (orig & 7) * 160 + (orig >> 3);

    const int pq = wg & 3;
    const int b  = (wg >> 2) & 3;
    const int e  = (wg >> 4) & 15;
    const int x  = wg >> 8;

    const int tid  = threadIdx.x;
    const int lane = tid & 63;
    const int wv   = tid >> 6;
    const int l15  = lane & 15;
    const int lg   = lane >> 4;

    const int rowbase = (wv >> 1) * 32;   // wave's 32-row half
    const int fhalf   = wv & 1;           // wave's 64-col half

    const float temp = fabsf(temperature[0]) + 1e-6f;

    // fusion softmax -> weight for this x
    float fwx;
    {
        float fv[NDIR], fmx = -1e30f, fsum = 0.f;
        #pragma unroll
        for (int i = 0; i < NDIR; ++i) { fv[i] = fusion[i]; fmx = fmaxf(fmx, fv[i]); }
        #pragma unroll
        for (int i = 0; i < NDIR; ++i) { fv[i] = __expf(fv[i] - fmx); fsum += fv[i]; }
        fwx = fv[x] / fsum;
    }

    int rt[W_]; float bf3[W_];
    #pragma unroll
    for (int w = 0; w < W_; ++w) {
        rt[w] = routes.r[e][w];
        float bv_ = betas[e * E_ + rt[w]];
        bf3[w] = (rt[w] == e) ? 1.0f : 1.0f / (1.0f + __expf(-bv_));
    }

    // stage s = K * beta (768 floats)
    #pragma unroll
    for (int w = 0; w < W_; ++w)
        s_lds[w * P_ + tid] =
            K[(((size_t)(x * E_ + rt[w])) * B_ + b) * P_ + tid] * bf3[w];

    // q rows this lane contributes to
    const float* Qb = Q + (((size_t)(x * E_ + e)) * B_ + b) * P_ + pq * ROWS + rowbase;
    float q2[2];
    q2[0] = Qb[l15] / temp;
    q2[1] = Qb[16 + l15] / temp;

    // Vt slab pointers (bf16 units)
    const unsigned short* vs0 = Vt + ((size_t)(x * E_ + rt[0]) * B_ + b) * (P_ * D_);
    const unsigned short* vs1 = Vt + ((size_t)(x * E_ + rt[1]) * B_ + b) * (P_ * D_);
    const unsigned short* vs2 = Vt + ((size_t)(x * E_ + rt[2]) * B_ + b) * (P_ * D_);

    // ---- stage addressing ----
    // lane covers f = wv*8 + (lane>>3) + h*32, 16B chunk j = lane&7;
    // source k-chunk = j ^ (lane>>3)  (inverse-swizzle so LDS is swizzled);
    // dest (wave-uniform) = vbuf + wv*1024 + h*4096, HW adds lane*16.
    const int src_off = (wv * 8 + (lane >> 3)) * P_ + ((lane & 7) ^ (lane >> 3)) * 8;

    // ---- read addressing: byte = f*128 + ((s*4+lg)^(f&7))*16, f = c'*16+l15 ----
    const int rdbase = fhalf * 8192 + l15 * 128 + ((lg ^ (l15 & 7)) * 16);

    #define STAGE(bi, t_) do {                                                   \
        const unsigned short* sl_ = ((t_) >> 2) == 0 ? vs0                       \
                                  : (((t_) >> 2) == 1 ? vs1 : vs2);              \
        const unsigned short* sb_ = sl_ + (((t_) & 3) * 64) + src_off;           \
        char* db_ = (char*)vbuf[bi] + wv * 1024;                                 \
        gld16(sb_,          db_);                                                \
        gld16(sb_ +  8192,  db_ + 4096);                                         \
        gld16(sb_ + 16384,  db_ + 8192);                                         \
        gld16(sb_ + 24576,  db_ + 12288);                                        \
    } while (0)

    STAGE(0, 0);
    __syncthreads();   // s_lds visible + chunk 0 landed

    f32x4 acc[2][4];
    #pragma unroll
    for (int fr = 0; fr < 2; ++fr)
        #pragma unroll
        for (int c = 0; c < 4; ++c)
            acc[fr][c] = (f32x4){0.f, 0.f, 0.f, 0.f};
    float den[2] = {0.f, 0.f};

    #pragma unroll
    for (int t = 0; t < NT; ++t) {
        const int cur = t & 1;
        if (t < NT - 1) STAGE(cur ^ 1, t + 1);   // in flight during compute

        #pragma unroll
        for (int s = 0; s < 2; ++s) {
            // ---- A fragments: 16 exps (s octet broadcast from s_lds) ----
            const float* sp = s_lds + (t >> 2) * P_ + (t & 3) * 64 + s * 32 + 8 * lg;
            f32x8 sv;
            {
                const float4 s0_ = *reinterpret_cast<const float4*>(sp);
                const float4 s1_ = *reinterpret_cast<const float4*>(sp + 4);
                sv[0] = s0_.x; sv[1] = s0_.y; sv[2] = s0_.z; sv[3] = s0_.w;
                sv[4] = s1_.x; sv[5] = s1_.y; sv[6] = s1_.z; sv[7] = s1_.w;
            }
            short8 af0, af1;
            {
                f32x8 e0, e1;
                #pragma unroll
                for (int i = 0; i < 8; ++i) e0[i] = __expf(q2[0] * sv[i]);
                #pragma unroll
                for (int i = 0; i < 8; ++i) e1[i] = __expf(q2[1] * sv[i]);
                den[0] += ((e0[0]+e0[1]) + (e0[2]+e0[3])) + ((e0[4]+e0[5]) + (e0[6]+e0[7]));
                den[1] += ((e1[0]+e1[1]) + (e1[2]+e1[3])) + ((e1[4]+e1[5]) + (e1[6]+e1[7]));
                af0 = pack8(e0);
                af1 = pack8(e1);
            }

            // ---- 4 col-groups: swizzled ds_read_b128 + 2 MFMAs each ----
            #pragma unroll
            for (int c = 0; c < 4; ++c) {
                const short8 bf = *reinterpret_cast<const short8*>(
                    &vbuf[cur][(rdbase ^ (s << 6)) + c * 2048]);
                acc[0][c] = __builtin_amdgcn_mfma_f32_16x16x32_bf16(
                    af0, bf, acc[0][c], 0, 0, 0);
                acc[1][c] = __builtin_amdgcn_mfma_f32_16x16x32_bf16(
                    af1, bf, acc[1][c], 0, 0, 0);
            }
        }
        __syncthreads();   // drains next-chunk loads; syncs dbuf swap
    }
    #undef STAGE

    // ---- full-row denominators: sum across the 4 lane-groups ----
    #pragma unroll
    for (int fr = 0; fr < 2; ++fr) {
        den[fr] += __shfl_xor(den[fr], 16);
        den[fr] += __shfl_xor(den[fr], 32);
    }

    // ---- scale + write ----
    const size_t obase = ((((size_t)b * E_ + e) * NPQ) + pq) * (ROWS * D_);
    float* __restrict__ tgt = ATOMIC
        ? target
        : target + (size_t)x * ((size_t)B_ * E_ * NPQ * ROWS * D_);

    #pragma unroll
    for (int fr = 0; fr < 2; ++fr) {
        #pragma unroll
        for (int r = 0; r < 4; ++r) {
            const float dr = __shfl(den[fr], 4 * lg + r);   // den of row fr*16+4*lg+r
            const float sc = fwx / dr;
            const int row = rowbase + fr * 16 + 4 * lg + r;
            float* op = tgt + obase + (size_t)row * D_ + fhalf * 64;
            #pragma unroll
            for (int c = 0; c < 4; ++c) {
                const float v = sc * acc[fr][c][r];
                if (ATOMIC) atomicAdd(op + c * 16 + l15, v);
                else        op[c * 16 + l15] = v;
            }
        }
    }
}

__global__ __launch_bounds__(256) void reduce5_kernel(
    const float* __restrict__ part, float* __restrict__ out)
{
    const size_t i = (size_t)blockIdx.x * 256 + threadIdx.x;   // float4 index
    const float4* __restrict__ p = reinterpret_cast<const float4*>(part);
    float4 a = p[i];
    #pragma unroll
    for (int x = 1; x < NDIR; ++x) {
        float4 t = p[(size_t)x * 524288 + i];
        a.x += t.x; a.y += t.y; a.z += t.z; a.w += t.w;
    }
    reinterpret_cast<float4*>(out)[i] = a;
}

extern "C" void kernel_launch(void* const* d_in, const int* in_sizes, int n_in,
                              void* d_out, int out_size, void* d_ws, size_t ws_size,
                              hipStream_t stream) {
    (void)in_sizes; (void)n_in;
    RoutesArg R = make_routes();
    const float* Q     = (const float*)d_in[0];
    const float* K     = (const float*)d_in[1];
    const float* V     = (const float*)d_in[2];
    const float* betas = (const float*)d_in[3];
    const float* tempr = (const float*)d_in[4];
    const float* fuse  = (const float*)d_in[5];
    float* out = (float*)d_out;

    const size_t vt_bytes   = (size_t)NDIR * E_ * B_ * P_ * D_ * 2;            // ~21 MB
    const size_t part_bytes = (size_t)NDIR * B_ * E_ * NPQ * ROWS * D_ * 4;    // ~42 MB

    dim3 grid(NDIR * E_ * B_ * NPQ);   // 1280
    dim3 block(256);

    if (ws_size >= vt_bytes + part_bytes) {
        unsigned short* Vt = (unsigned short*)d_ws;
        float* part = (float*)((char*)d_ws + vt_bytes);
        hipLaunchKernelGGL(vt_prep_kernel, dim3(1280), block, 0, stream, V, Vt);
        hipLaunchKernelGGL((cantor_partial3_kernel<false>), grid, block, 0, stream,
                           Q, K, Vt, betas, tempr, fuse, part, R);
        hipLaunchKernelGGL(reduce5_kernel, dim3(2048), block, 0, stream,
                           part, out);
    } else {
        unsigned short* Vt = (unsigned short*)d_ws;   // ws >= 21MB always observed
        (void)hipMemsetAsync(d_out, 0, (size_t)out_size * 4, stream);
        hipLaunchKernelGGL(vt_prep_kernel, dim3(1280), block, 0, stream, V, Vt);
        hipLaunchKernelGGL((cantor_partial3_kernel<true>), grid, block, 0, stream,
                           Q, K, Vt, betas, tempr, fuse, out, R);
    }
}

// Round 17
// 76.471 us; speedup vs baseline: 2.5437x; 1.3702x over previous
//
#include <hip/hip_runtime.h>
#include <math.h>

#define NDIR 5
#define E_ 16
#define W_ 3
#define D_ 128
#define P_ 256
#define B_ 4
#define ROWS 64
#define NPQ 4
#define NT 12        // k64-chunks: W_*P_/64

typedef __attribute__((ext_vector_type(8))) short short8;
typedef __attribute__((ext_vector_type(4))) float f32x4;
typedef __attribute__((ext_vector_type(8))) float f32x8;

struct RoutesArg { int r[E_][W_]; };

// Replicates Python _cantor_coord + stable argsort route construction on host.
static RoutesArg make_routes() {
    float coords[E_];
    for (int i = 0; i < E_; ++i) {
        double x = (double)i / (double)(E_ - 1);
        if (x < 1e-6) x = 1e-6;
        if (x > 1.0 - 1e-6) x = 1.0 - 1e-6;
        double val = 0.0, factor = 0.5;
        for (int d = 0; d < 8; ++d) {
            x *= 3.0;
            int digit = (int)x;
            x -= (double)digit;
            if (digit == 2) val += factor;
            factor *= 0.5;
        }
        coords[i] = (float)val;
    }
    RoutesArg R;
    for (int i = 0; i < E_; ++i) {
        float d[E_]; int idx[E_];
        for (int j = 0; j < E_; ++j) { d[j] = fabsf(coords[j] - coords[i]); idx[j] = j; }
        for (int a = 1; a < E_; ++a) {
            int key = idx[a]; float kd = d[key];
            int c = a - 1;
            while (c >= 0 && d[idx[c]] > kd) { idx[c + 1] = idx[c]; --c; }
            idx[c + 1] = key;
        }
        int top[W_] = { idx[0], idx[1], idx[2] };
        if (top[0] > top[1]) { int t = top[0]; top[0] = top[1]; top[1] = t; }
        if (top[1] > top[2]) { int t = top[1]; top[1] = top[2]; top[2] = t; }
        if (top[0] > top[1]) { int t = top[0]; top[0] = top[1]; top[1] = t; }
        for (int w = 0; w < W_; ++w) R.r[i][w] = top[w];
    }
    return R;
}

// exact RNE float->bf16 (finite inputs only)
static __device__ __forceinline__ unsigned short f2bf(float f) {
    union { float f; unsigned int u; } v; v.f = f;
    unsigned int r = (v.u + 0x7FFFu + ((v.u >> 16) & 1u)) >> 16;
    return (unsigned short)r;
}

// HW packed f32->bf16 (RNE), proven correct in Rounds 6/7/12/13/16.
static __device__ __forceinline__ unsigned int cvt_pk_bf16(float lo, float hi) {
    unsigned int r;
    asm("v_cvt_pk_bf16_f32 %0, %1, %2" : "=v"(r) : "v"(lo), "v"(hi));
    return r;
}

// By-VALUE vector in, literal indices only -> stays in registers (rule #20).
static __device__ __forceinline__ short8 pack8(f32x8 a) {
    union { unsigned int u[4]; short8 s; } cv;
    cv.u[0] = cvt_pk_bf16(a[0], a[1]);
    cv.u[1] = cvt_pk_bf16(a[2], a[3]);
    cv.u[2] = cvt_pk_bf16(a[4], a[5]);
    cv.u[3] = cvt_pk_bf16(a[6], a[7]);
    return cv.s;
}

// async global->LDS, 16B per lane (dest = wave-uniform base + lane*16)
static __device__ __forceinline__ void gld16(const void* g, void* l) {
    __builtin_amdgcn_global_load_lds(
        (const __attribute__((address_space(1))) unsigned int*)g,
        (__attribute__((address_space(3))) unsigned int*)l,
        16, 0, 0);
}

// ---- prep: V fp32 [slab][k=256][f=128] -> Vt bf16 [slab][f=128][k=256] ----
__global__ __launch_bounds__(256) void vt_prep_kernel(
    const float* __restrict__ V, unsigned short* __restrict__ Vt)
{
    const int sub  = blockIdx.x & 3;          // k-quarter
    const int slab = blockIdx.x >> 2;         // 0..319
    const int tid  = threadIdx.x;
    const float4* __restrict__ src =
        reinterpret_cast<const float4*>(V + (size_t)slab * (P_ * D_));
    unsigned short* __restrict__ dst = Vt + (size_t)slab * (P_ * D_);
    #pragma unroll
    for (int it = 0; it < 8; ++it) {
        const int idx4 = sub * 2048 + it * 256 + tid;
        const int k  = idx4 >> 5;
        const int f4 = (idx4 & 31) * 4;
        const float4 v = src[idx4];
        dst[(size_t)(f4 + 0) * P_ + k] = f2bf(v.x);
        dst[(size_t)(f4 + 1) * P_ + k] = f2bf(v.y);
        dst[(size_t)(f4 + 2) * P_ + k] = f2bf(v.z);
        dst[(size_t)(f4 + 3) * P_ + k] = f2bf(v.w);
    }
}

// Block = (x, e, b, pq-tile of 64 rows); 1280 blocks, 4 waves, 2x2 wave split
// (32-row half x 64-col half). Vt k64-tile [128f][64k] bf16 staged to LDS via
// global_load_lds (16KB, dbuf), XOR-swizzled source for conflict-free reads.
// One barrier per chunk (m97/T3). t-loop NOT unrolled (R16: full unroll ->
// 212 VGPR -> 1 block/CU -> serial barrier drains); min-waves 4 caps VGPR.
template <bool ATOMIC>
__global__ __launch_bounds__(256, 4) void cantor_partial3_kernel(
    const float* __restrict__ Q, const float* __restrict__ K,
    const unsigned short* __restrict__ Vt, const float* __restrict__ betas,
    const float* __restrict__ temperature, const float* __restrict__ fusion,
    float* __restrict__ target, RoutesArg routes)
{
    __shared__ float s_lds[W_ * P_];                         // 3 KB
    __shared__ __align__(16) unsigned char vbuf[2][16384];   // 32 KB

    // XCD-bijective swizzle: 1280 blocks = 8 XCDs x 160
    const int orig = blockIdx.x;
    const int wg   = (orig & 7) * 160 + (orig >> 3);

    const int pq = wg & 3;
    const int b  = (wg >> 2) & 3;
    const int e  = (wg >> 4) & 15;
    const int x  = wg >> 8;

    const int tid  = threadIdx.x;
    const int lane = tid & 63;
    const int wv   = tid >> 6;
    const int l15  = lane & 15;
    const int lg   = lane >> 4;

    const int rowbase = (wv >> 1) * 32;   // wave's 32-row half
    const int fhalf   = wv & 1;           // wave's 64-col half

    const float temp = fabsf(temperature[0]) + 1e-6f;

    // fusion softmax -> weight for this x
    float fwx;
    {
        float fv[NDIR], fmx = -1e30f, fsum = 0.f;
        #pragma unroll
        for (int i = 0; i < NDIR; ++i) { fv[i] = fusion[i]; fmx = fmaxf(fmx, fv[i]); }
        #pragma unroll
        for (int i = 0; i < NDIR; ++i) { fv[i] = __expf(fv[i] - fmx); fsum += fv[i]; }
        fwx = fv[x] / fsum;
    }

    int rt[W_]; float bf3[W_];
    #pragma unroll
    for (int w = 0; w < W_; ++w) {
        rt[w] = routes.r[e][w];
        float bv_ = betas[e * E_ + rt[w]];
        bf3[w] = (rt[w] == e) ? 1.0f : 1.0f / (1.0f + __expf(-bv_));
    }

    // stage s = K * beta (768 floats)
    #pragma unroll
    for (int w = 0; w < W_; ++w)
        s_lds[w * P_ + tid] =
            K[(((size_t)(x * E_ + rt[w])) * B_ + b) * P_ + tid] * bf3[w];

    // q rows this lane contributes to
    const float* Qb = Q + (((size_t)(x * E_ + e)) * B_ + b) * P_ + pq * ROWS + rowbase;
    float q2[2];
    q2[0] = Qb[l15] / temp;
    q2[1] = Qb[16 + l15] / temp;

    // Vt slab pointers (bf16 units)
    const unsigned short* vs0 = Vt + ((size_t)(x * E_ + rt[0]) * B_ + b) * (P_ * D_);
    const unsigned short* vs1 = Vt + ((size_t)(x * E_ + rt[1]) * B_ + b) * (P_ * D_);
    const unsigned short* vs2 = Vt + ((size_t)(x * E_ + rt[2]) * B_ + b) * (P_ * D_);

    // ---- stage addressing ----
    // lane covers f = wv*8 + (lane>>3) + h*32, 16B chunk j = lane&7;
    // source k-chunk = j ^ (lane>>3)  (inverse-swizzle so LDS is swizzled);
    // dest (wave-uniform) = vbuf + wv*1024 + h*4096, HW adds lane*16.
    const int src_off = (wv * 8 + (lane >> 3)) * P_ + ((lane & 7) ^ (lane >> 3)) * 8;

    // ---- read addressing: byte = f*128 + ((s*4+lg)^(f&7))*16, f = c'*16+l15 ----
    const int rdbase = fhalf * 8192 + l15 * 128 + ((lg ^ (l15 & 7)) * 16);

    #define STAGE(bi, t_) do {                                                   \
        const unsigned short* sl_ = ((t_) >> 2) == 0 ? vs0                       \
                                  : (((t_) >> 2) == 1 ? vs1 : vs2);              \
        const unsigned short* sb_ = sl_ + (((t_) & 3) * 64) + src_off;           \
        char* db_ = (char*)vbuf[bi] + wv * 1024;                                 \
        gld16(sb_,          db_);                                                \
        gld16(sb_ +  8192,  db_ + 4096);                                         \
        gld16(sb_ + 16384,  db_ + 8192);                                         \
        gld16(sb_ + 24576,  db_ + 12288);                                        \
    } while (0)

    STAGE(0, 0);
    __syncthreads();   // s_lds visible + chunk 0 landed

    f32x4 acc[2][4];
    #pragma unroll
    for (int fr = 0; fr < 2; ++fr)
        #pragma unroll
        for (int c = 0; c < 4; ++c)
            acc[fr][c] = (f32x4){0.f, 0.f, 0.f, 0.f};
    float den[2] = {0.f, 0.f};

    #pragma unroll 1   // R16 lesson: full unroll -> 212 VGPR -> 1 block/CU
    for (int t = 0; t < NT; ++t) {
        const int cur = t & 1;
        if (t < NT - 1) STAGE(cur ^ 1, t + 1);   // in flight during compute

        #pragma unroll
        for (int s = 0; s < 2; ++s) {
            // ---- A fragments: 16 exps (s octet broadcast from s_lds) ----
            const float* sp = s_lds + (t >> 2) * P_ + (t & 3) * 64 + s * 32 + 8 * lg;
            f32x8 sv;
            {
                const float4 s0_ = *reinterpret_cast<const float4*>(sp);
                const float4 s1_ = *reinterpret_cast<const float4*>(sp + 4);
                sv[0] = s0_.x; sv[1] = s0_.y; sv[2] = s0_.z; sv[3] = s0_.w;
                sv[4] = s1_.x; sv[5] = s1_.y; sv[6] = s1_.z; sv[7] = s1_.w;
            }
            short8 af0, af1;
            {
                f32x8 e0, e1;
                #pragma unroll
                for (int i = 0; i < 8; ++i) e0[i] = __expf(q2[0] * sv[i]);
                #pragma unroll
                for (int i = 0; i < 8; ++i) e1[i] = __expf(q2[1] * sv[i]);
                den[0] += ((e0[0]+e0[1]) + (e0[2]+e0[3])) + ((e0[4]+e0[5]) + (e0[6]+e0[7]));
                den[1] += ((e1[0]+e1[1]) + (e1[2]+e1[3])) + ((e1[4]+e1[5]) + (e1[6]+e1[7]));
                af0 = pack8(e0);
                af1 = pack8(e1);
            }

            // ---- 4 col-groups: swizzled ds_read_b128 + 2 MFMAs each ----
            #pragma unroll
            for (int c = 0; c < 4; ++c) {
                const short8 bf = *reinterpret_cast<const short8*>(
                    &vbuf[cur][(rdbase ^ (s << 6)) + c * 2048]);
                acc[0][c] = __builtin_amdgcn_mfma_f32_16x16x32_bf16(
                    af0, bf, acc[0][c], 0, 0, 0);
                acc[1][c] = __builtin_amdgcn_mfma_f32_16x16x32_bf16(
                    af1, bf, acc[1][c], 0, 0, 0);
            }
        }
        __syncthreads();   // drains next-chunk loads; syncs dbuf swap
    }
    #undef STAGE

    // ---- full-row denominators: sum across the 4 lane-groups ----
    #pragma unroll
    for (int fr = 0; fr < 2; ++fr) {
        den[fr] += __shfl_xor(den[fr], 16);
        den[fr] += __shfl_xor(den[fr], 32);
    }

    // ---- scale + write ----
    const size_t obase = ((((size_t)b * E_ + e) * NPQ) + pq) * (ROWS * D_);
    float* __restrict__ tgt = ATOMIC
        ? target
        : target + (size_t)x * ((size_t)B_ * E_ * NPQ * ROWS * D_);

    #pragma unroll
    for (int fr = 0; fr < 2; ++fr) {
        #pragma unroll
        for (int r = 0; r < 4; ++r) {
            const float dr = __shfl(den[fr], 4 * lg + r);   // den of row fr*16+4*lg+r
            const float sc = fwx / dr;
            const int row = rowbase + fr * 16 + 4 * lg + r;
            float* op = tgt + obase + (size_t)row * D_ + fhalf * 64;
            #pragma unroll
            for (int c = 0; c < 4; ++c) {
                const float v = sc * acc[fr][c][r];
                if (ATOMIC) atomicAdd(op + c * 16 + l15, v);
                else        op[c * 16 + l15] = v;
            }
        }
    }
}

__global__ __launch_bounds__(256) void reduce5_kernel(
    const float* __restrict__ part, float* __restrict__ out)
{
    const size_t i = (size_t)blockIdx.x * 256 + threadIdx.x;   // float4 index
    const float4* __restrict__ p = reinterpret_cast<const float4*>(part);
    float4 a = p[i];
    #pragma unroll
    for (int x = 1; x < NDIR; ++x) {
        float4 t = p[(size_t)x * 524288 + i];
        a.x += t.x; a.y += t.y; a.z += t.z; a.w += t.w;
    }
    reinterpret_cast<float4*>(out)[i] = a;
}

extern "C" void kernel_launch(void* const* d_in, const int* in_sizes, int n_in,
                              void* d_out, int out_size, void* d_ws, size_t ws_size,
                              hipStream_t stream) {
    (void)in_sizes; (void)n_in;
    RoutesArg R = make_routes();
    const float* Q     = (const float*)d_in[0];
    const float* K     = (const float*)d_in[1];
    const float* V     = (const float*)d_in[2];
    const float* betas = (const float*)d_in[3];
    const float* tempr = (const float*)d_in[4];
    const float* fuse  = (const float*)d_in[5];
    float* out = (float*)d_out;

    const size_t vt_bytes   = (size_t)NDIR * E_ * B_ * P_ * D_ * 2;            // ~21 MB
    const size_t part_bytes = (size_t)NDIR * B_ * E_ * NPQ * ROWS * D_ * 4;    // ~42 MB

    dim3 grid(NDIR * E_ * B_ * NPQ);   // 1280
    dim3 block(256);

    if (ws_size >= vt_bytes + part_bytes) {
        unsigned short* Vt = (unsigned short*)d_ws;
        float* part = (float*)((char*)d_ws + vt_bytes);
        hipLaunchKernelGGL(vt_prep_kernel, dim3(1280), block, 0, stream, V, Vt);
        hipLaunchKernelGGL((cantor_partial3_kernel<false>), grid, block, 0, stream,
                           Q, K, Vt, betas, tempr, fuse, part, R);
        hipLaunchKernelGGL(reduce5_kernel, dim3(2048), block, 0, stream,
                           part, out);
    } else {
        unsigned short* Vt = (unsigned short*)d_ws;   // ws >= 21MB always observed
        (void)hipMemsetAsync(d_out, 0, (size_t)out_size * 4, stream);
        hipLaunchKernelGGL(vt_prep_kernel, dim3(1280), block, 0, stream, V, Vt);
        hipLaunchKernelGGL((cantor_partial3_kernel<true>), grid, block, 0, stream,
                           Q, K, Vt, betas, tempr, fuse, out, R);
    }
}